// Round 1
// baseline (121.287 us; speedup 1.0000x reference)
//
#include <hip/hip_runtime.h>
#include <math.h>

#define UDIM 512
#define DIN  256
#define BATCH 128
#define EPSV 1e-3f

// ---------------------------------------------------------------------------
// K1: pre = prev @ W_h + inputs @ C ; h = tanh(pre + bias)
// grid = BATCH*2 blocks of 256 threads; block handles (b, half of v)
// ---------------------------------------------------------------------------
__global__ __launch_bounds__(256) void k_pre(
    const float* __restrict__ inputs, const float* __restrict__ prev,
    const float* __restrict__ C, const float* __restrict__ Wh,
    const float* __restrict__ bias, float* __restrict__ pre, float* __restrict__ h)
{
    const int b = blockIdx.x >> 1;
    const int v = ((blockIdx.x & 1) << 8) + threadIdx.x;

    __shared__ float sprev[UDIM];
    __shared__ float sinp[DIN];
    for (int i = threadIdx.x; i < UDIM; i += 256) sprev[i] = prev[b * UDIM + i];
    sinp[threadIdx.x] = inputs[b * DIN + threadIdx.x];
    __syncthreads();

    float acc = 0.f;
#pragma unroll 8
    for (int u = 0; u < UDIM; ++u) acc = fmaf(sprev[u], Wh[u * UDIM + v], acc);
#pragma unroll 8
    for (int i = 0; i < DIN; ++i)  acc = fmaf(sinp[i], C[i * UDIM + v], acc);

    pre[b * UDIM + v] = acc;
    h[b * UDIM + v]   = tanhf(acc + bias[v]);
}

// ---------------------------------------------------------------------------
// K2: per-batch mega kernel.
//   step 0: stream A[b], write A_new[b] = 0.9A + 0.5 h h^T, accumulate h@A
//   steps 1,2: re-stream A[b] (L3-resident), accumulate x@A
//   y = 0.9*(x@A) + 0.5*(x.h)*h ; hs = tanh(pre + y) ; x = LN(hs)
// grid = BATCH blocks of 1024 threads (8 u-segments x 128 v-groups of 4)
// ---------------------------------------------------------------------------
__global__ __launch_bounds__(1024) void k_steps(
    const float* __restrict__ A, const float* __restrict__ pre,
    const float* __restrict__ h, const float* __restrict__ gamma,
    const float* __restrict__ beta, float* __restrict__ Anew,
    float* __restrict__ out)
{
    const int b    = blockIdx.x;
    const int t    = threadIdx.x;
    const int lane = t & 63;
    const int wave = t >> 6;        // 0..15
    const int vg   = t & 127;
    const int v0   = vg << 2;       // v base (float4)
    const int useg = t >> 7;        // 0..7

    __shared__ __align__(16) float sh[UDIM];      // h row (fixed)
    __shared__ __align__(16) float sx[UDIM];      // current state x
    __shared__ __align__(16) float spre[UDIM];    // pre row
    __shared__ __align__(16) float spart[8][UDIM];// matvec partials
    __shared__ float sred[16];
    __shared__ float sbc[4];                      // 0:mean 1:rstd 2:dot

    if (t < UDIM) {
        float hv = h[(size_t)b * UDIM + t];
        sh[t] = hv; sx[t] = hv;
        spre[t] = pre[(size_t)b * UDIM + t];
    }
    __syncthreads();

    const float4 hv4 = *(const float4*)(sh + v0);
    const float* __restrict__ Ab  = A    + (size_t)b * UDIM * UDIM;
    float*       __restrict__ Anb = Anew + (size_t)b * UDIM * UDIM;
    const size_t rowbase = (size_t)(useg * 64) * UDIM + v0;

    for (int step = 0; step < 3; ++step) {
        // ---- dot = x . h (block reduce over t<512) ----
        {
            float p = (t < UDIM) ? sx[t] * sh[t] : 0.f;
#pragma unroll
            for (int off = 32; off; off >>= 1) p += __shfl_xor(p, off, 64);
            if (lane == 0) sred[wave] = p;
            __syncthreads();
            if (t == 0) {
                float d = 0.f;
#pragma unroll
                for (int i = 0; i < 8; ++i) d += sred[i];
                sbc[2] = d;
            }
            __syncthreads();
        }

        // ---- stream A[b]: acc = x @ A (per-thread 4 columns, 64 rows) ----
        float4 acc = make_float4(0.f, 0.f, 0.f, 0.f);
        if (step == 0) {
#pragma unroll 4
            for (int k = 0; k < 64; ++k) {
                const float4 a4 = *(const float4*)(Ab + rowbase + (size_t)k * UDIM);
                const float xu = sh[useg * 64 + k];       // x == h in step 0
                acc.x = fmaf(xu, a4.x, acc.x);
                acc.y = fmaf(xu, a4.y, acc.y);
                acc.z = fmaf(xu, a4.z, acc.z);
                acc.w = fmaf(xu, a4.w, acc.w);
                const float s = 0.5f * xu;
                float4 an;
                an.x = fmaf(s, hv4.x, 0.9f * a4.x);
                an.y = fmaf(s, hv4.y, 0.9f * a4.y);
                an.z = fmaf(s, hv4.z, 0.9f * a4.z);
                an.w = fmaf(s, hv4.w, 0.9f * a4.w);
                *(float4*)(Anb + rowbase + (size_t)k * UDIM) = an;
            }
        } else {
#pragma unroll 4
            for (int k = 0; k < 64; ++k) {
                const float4 a4 = *(const float4*)(Ab + rowbase + (size_t)k * UDIM);
                const float xu = sx[useg * 64 + k];
                acc.x = fmaf(xu, a4.x, acc.x);
                acc.y = fmaf(xu, a4.y, acc.y);
                acc.z = fmaf(xu, a4.z, acc.z);
                acc.w = fmaf(xu, a4.w, acc.w);
            }
        }
        *(float4*)(&spart[useg][v0]) = acc;
        __syncthreads();

        // ---- combine, tanh, layernorm (threads 0..511, one v each) ----
        float hs = 0.f;
        if (t < UDIM) {
            float y = 0.f;
#pragma unroll
            for (int s = 0; s < 8; ++s) y += spart[s][t];
            y = 0.9f * y + 0.5f * sbc[2] * sh[t];
            hs = tanhf(spre[t] + y);
            float s1 = hs, s2 = hs * hs;
#pragma unroll
            for (int off = 32; off; off >>= 1) {
                s1 += __shfl_xor(s1, off, 64);
                s2 += __shfl_xor(s2, off, 64);
            }
            if (lane == 0) { sred[wave] = s1; sred[8 + wave] = s2; }
        }
        __syncthreads();
        if (t == 0) {
            float m = 0.f, q = 0.f;
#pragma unroll
            for (int i = 0; i < 8; ++i) { m += sred[i]; q += sred[8 + i]; }
            m *= (1.f / UDIM);
            q = q * (1.f / UDIM) - m * m;
            sbc[0] = m;
            sbc[1] = rsqrtf(q + EPSV);
        }
        __syncthreads();
        if (t < UDIM) {
            float xn = (hs - sbc[0]) * sbc[1] * gamma[t] + beta[t];
            sx[t] = xn;
            if (step == 2) out[(size_t)b * UDIM + t] = xn;
        }
        __syncthreads();
    }
}

// ---------------------------------------------------------------------------
extern "C" void kernel_launch(void* const* d_in, const int* in_sizes, int n_in,
                              void* d_out, int out_size, void* d_ws, size_t ws_size,
                              hipStream_t stream) {
    const float* inputs = (const float*)d_in[0];
    const float* prev   = (const float*)d_in[1];
    const float* A      = (const float*)d_in[2];
    const float* C      = (const float*)d_in[3];
    const float* Wh     = (const float*)d_in[4];
    const float* bias   = (const float*)d_in[5];
    const float* gamma  = (const float*)d_in[6];
    const float* beta   = (const float*)d_in[7];

    float* out  = (float*)d_out;                 // (128,512)
    float* Anew = out + (size_t)BATCH * UDIM;    // (128,512,512)

    float* pre = (float*)d_ws;                   // (128,512)
    float* h   = pre + (size_t)BATCH * UDIM;     // (128,512)

    k_pre  <<<BATCH * 2, 256, 0, stream>>>(inputs, prev, C, Wh, bias, pre, h);
    k_steps<<<BATCH, 1024, 0, stream>>>(A, pre, h, gamma, beta, Anew, out);
}